// Round 2
// baseline (361.707 us; speedup 1.0000x reference)
//
#include <hip/hip_runtime.h>
#include <math.h>

#define TOKENS 16384
#define DMODEL 2048
#define NEXP   64
#define TOPK   8
#define BM     64
#define BK     32
#define PAD    4   // row stride 68 floats = 272 B -> every row 16B-aligned (ds_read_b128)

// Kernel 1: partial logits. part[kc][t][e] = sum_{k in chunk kc} x[t][k]*W[e][k]
// 64 tokens x 64 experts per 256-thread block, 4x4 register tile, grid.y = ksplit.
// fp32 FMA chunks of 8 flushed into fp64 accumulators (top-k index stability).
__global__ __launch_bounds__(256, 4) void router_gemm(
    const float* __restrict__ x, const float* __restrict__ W,
    float* __restrict__ part, int kchunk)
{
    __shared__ float xsT[BK][BM + PAD];    // transposed: xsT[k][token]
    __shared__ float wsT[BK][NEXP + PAD];  // wsT[k][expert]

    const int tid = threadIdx.x;
    const int kq  = tid & 7;    // float4 slot along BK
    const int row = tid >> 3;   // 0..31: token row / expert row for staging
    const int ty  = tid >> 4;   // 0..15 token quad
    const int tx  = tid & 15;   // 0..15 expert quad
    const size_t tokBase = (size_t)blockIdx.x * BM;
    const int    kc      = blockIdx.y;
    const size_t kbase   = (size_t)kc * (size_t)kchunk;

    double accd[4][4];
    float  accf[4][4];
#pragma unroll
    for (int i = 0; i < 4; ++i)
#pragma unroll
        for (int j = 0; j < 4; ++j) { accd[i][j] = 0.0; accf[i][j] = 0.0f; }

    for (int k0 = 0; k0 < kchunk; k0 += BK) {
        const size_t koff = kbase + (size_t)k0 + kq * 4;
        const float4 xa = *(const float4*)(x + (tokBase + row) * DMODEL + koff);
        const float4 xb = *(const float4*)(x + (tokBase + row + 32) * DMODEL + koff);
        const float4 wa = *(const float4*)(W + (size_t)row * DMODEL + koff);
        const float4 wb = *(const float4*)(W + (size_t)(row + 32) * DMODEL + koff);
        __syncthreads();   // previous tile's readers done before overwrite
        xsT[kq * 4 + 0][row] = xa.x; xsT[kq * 4 + 1][row] = xa.y;
        xsT[kq * 4 + 2][row] = xa.z; xsT[kq * 4 + 3][row] = xa.w;
        xsT[kq * 4 + 0][row + 32] = xb.x; xsT[kq * 4 + 1][row + 32] = xb.y;
        xsT[kq * 4 + 2][row + 32] = xb.z; xsT[kq * 4 + 3][row + 32] = xb.w;
        wsT[kq * 4 + 0][row] = wa.x; wsT[kq * 4 + 1][row] = wa.y;
        wsT[kq * 4 + 2][row] = wa.z; wsT[kq * 4 + 3][row] = wa.w;
        wsT[kq * 4 + 0][row + 32] = wb.x; wsT[kq * 4 + 1][row + 32] = wb.y;
        wsT[kq * 4 + 2][row + 32] = wb.z; wsT[kq * 4 + 3][row + 32] = wb.w;
        __syncthreads();

#pragma unroll
        for (int kk = 0; kk < BK; ++kk) {
            const float4 a = *(const float4*)(&xsT[kk][ty * 4]);  // ds_read_b128
            const float4 b = *(const float4*)(&wsT[kk][tx * 4]);  // ds_read_b128
            const float av[4] = {a.x, a.y, a.z, a.w};
            const float bv[4] = {b.x, b.y, b.z, b.w};
#pragma unroll
            for (int i = 0; i < 4; ++i)
#pragma unroll
                for (int j = 0; j < 4; ++j)
                    accf[i][j] = fmaf(av[i], bv[j], accf[i][j]);
            if ((kk & 7) == 7) {   // flush fp32 chunk into fp64 accumulator
#pragma unroll
                for (int i = 0; i < 4; ++i)
#pragma unroll
                    for (int j = 0; j < 4; ++j) {
                        accd[i][j] += (double)accf[i][j];
                        accf[i][j] = 0.0f;
                    }
            }
        }
    }

#pragma unroll
    for (int i = 0; i < 4; ++i) {
        const size_t tok = tokBase + ty * 4 + i;
        float4 o;
        o.x = (float)accd[i][0]; o.y = (float)accd[i][1];
        o.z = (float)accd[i][2]; o.w = (float)accd[i][3];
        *(float4*)(part + ((size_t)kc * TOKENS + tok) * NEXP + tx * 4) = o;
    }
}

// Kernel 2: wave-per-token fused split-K reduce + bias + top-8 + sigmoid.
// Lane e holds logit of expert e; 8 rounds of 64-lane butterfly argmax with
// ties broken toward the lower index (matches jax.lax.top_k stable ordering).
__global__ __launch_bounds__(256) void router_reduce_topk(
    const float* __restrict__ part, const float* __restrict__ bias,
    float* __restrict__ out_w, float* __restrict__ out_i, int ksplit)
{
    const int lane = threadIdx.x & 63;
    const int wid  = threadIdx.x >> 6;
    const size_t t = (size_t)blockIdx.x * 4 + wid;

    float v = bias[lane];
    for (int kc = 0; kc < ksplit; ++kc)
        v += part[((size_t)kc * TOKENS + t) * NEXP + lane];

    const int myi = lane;
    float bv = 0.0f; int bi = 0;
#pragma unroll
    for (int r = 0; r < TOPK; ++r) {
        float mv = v; int mi = myi;
#pragma unroll
        for (int off = 32; off > 0; off >>= 1) {
            const float ov = __shfl_xor(mv, off, 64);
            const int   oi = __shfl_xor(mi, off, 64);
            if (ov > mv || (ov == mv && oi < mi)) { mv = ov; mi = oi; }
        }
        if (lane == r)  { bv = mv; bi = mi; }  // lane r keeps rank-r result
        if (myi == mi)  { v = -INFINITY; }     // remove winner (mi is uniform)
    }

    if (lane < TOPK) {
        out_w[t * TOPK + lane] = 1.0f / (1.0f + expf(-bv));
        out_i[t * TOPK + lane] = (float)bi;
    }
}

extern "C" void kernel_launch(void* const* d_in, const int* in_sizes, int n_in,
                              void* d_out, int out_size, void* d_ws, size_t ws_size,
                              hipStream_t stream) {
    const float* x    = (const float*)d_in[0];   // [4,4096,2048]
    const float* W    = (const float*)d_in[1];   // [64,2048]
    const float* bias = (const float*)d_in[2];   // [64]
    float* out_w = (float*)d_out;                          // [16384,8]
    float* out_i = (float*)d_out + (size_t)TOKENS * TOPK;  // [16384,8] as float
    float* part  = (float*)d_ws;                 // [ksplit,16384,64] fp32

    int ksplit = 4;  // 4 blocks/CU -> 16 waves/CU; fall back if ws too small
    const size_t per = (size_t)TOKENS * NEXP * sizeof(float);
    if (ws_size < 4 * per) ksplit = (ws_size >= 2 * per) ? 2 : 1;
    const int kchunk = DMODEL / ksplit;

    dim3 grid(TOKENS / BM, ksplit);
    router_gemm<<<grid, 256, 0, stream>>>(x, W, part, kchunk);
    router_reduce_topk<<<TOKENS / 4, 256, 0, stream>>>(part, bias, out_w, out_i, ksplit);
}

// Round 3
// 234.559 us; speedup vs baseline: 1.5421x; 1.5421x over previous
//
#include <hip/hip_runtime.h>
#include <math.h>

#define TOKENS 16384
#define DMODEL 2048
#define NEXP   64
#define TOPK   8
#define BM     64
#define BK     32
#define PAD    4   // row stride 68 floats = 272 B -> rows 16B-aligned (ds_read_b128)

// Kernel 1: partial logits. part[kc][t][e] = sum_{k in chunk kc} x[t][k]*W[e][k]
// 64 tokens x 64 experts per 256-thread block, 4x4 register tile, grid.y = ksplit.
// fp32 FMA chunks of 16 flushed into fp64 accumulators: chunk rounding std
// ~2e-7 total — numpy-grade ordering, half the fp64 cost of chunk-8.
// NOTE: no min-waves launch bound — (256,4) in R2 forced VGPR=64 and spilled
// 430 MB of scratch to HBM (WRITE_SIZE counter), costing more than the
// occupancy it bought.
__global__ __launch_bounds__(256) void router_gemm(
    const float* __restrict__ x, const float* __restrict__ W,
    float* __restrict__ part, int kchunk)
{
    __shared__ float xsT[BK][BM + PAD];    // transposed: xsT[k][token]
    __shared__ float wsT[BK][NEXP + PAD];  // wsT[k][expert]

    const int tid = threadIdx.x;
    const int kq  = tid & 7;    // float4 slot along BK
    const int row = tid >> 3;   // 0..31: token row / expert row for staging
    const int ty  = tid >> 4;   // 0..15 token quad
    const int tx  = tid & 15;   // 0..15 expert quad
    const size_t tokBase = (size_t)blockIdx.x * BM;
    const int    kc      = blockIdx.y;
    const size_t kbase   = (size_t)kc * (size_t)kchunk;

    double accd[4][4];
    float  accf[4][4];
#pragma unroll
    for (int i = 0; i < 4; ++i)
#pragma unroll
        for (int j = 0; j < 4; ++j) { accd[i][j] = 0.0; accf[i][j] = 0.0f; }

    for (int k0 = 0; k0 < kchunk; k0 += BK) {
        const size_t koff = kbase + (size_t)k0 + kq * 4;
        const float4 xa = *(const float4*)(x + (tokBase + row) * DMODEL + koff);
        const float4 xb = *(const float4*)(x + (tokBase + row + 32) * DMODEL + koff);
        const float4 wa = *(const float4*)(W + (size_t)row * DMODEL + koff);
        const float4 wb = *(const float4*)(W + (size_t)(row + 32) * DMODEL + koff);
        __syncthreads();   // previous tile's readers done before overwrite
        xsT[kq * 4 + 0][row] = xa.x; xsT[kq * 4 + 1][row] = xa.y;
        xsT[kq * 4 + 2][row] = xa.z; xsT[kq * 4 + 3][row] = xa.w;
        xsT[kq * 4 + 0][row + 32] = xb.x; xsT[kq * 4 + 1][row + 32] = xb.y;
        xsT[kq * 4 + 2][row + 32] = xb.z; xsT[kq * 4 + 3][row + 32] = xb.w;
        wsT[kq * 4 + 0][row] = wa.x; wsT[kq * 4 + 1][row] = wa.y;
        wsT[kq * 4 + 2][row] = wa.z; wsT[kq * 4 + 3][row] = wa.w;
        wsT[kq * 4 + 0][row + 32] = wb.x; wsT[kq * 4 + 1][row + 32] = wb.y;
        wsT[kq * 4 + 2][row + 32] = wb.z; wsT[kq * 4 + 3][row + 32] = wb.w;
        __syncthreads();

#pragma unroll
        for (int kk = 0; kk < BK; ++kk) {
            const float4 a = *(const float4*)(&xsT[kk][ty * 4]);  // ds_read_b128
            const float4 b = *(const float4*)(&wsT[kk][tx * 4]);  // ds_read_b128
            const float av[4] = {a.x, a.y, a.z, a.w};
            const float bv[4] = {b.x, b.y, b.z, b.w};
#pragma unroll
            for (int i = 0; i < 4; ++i)
#pragma unroll
                for (int j = 0; j < 4; ++j)
                    accf[i][j] = fmaf(av[i], bv[j], accf[i][j]);
            if ((kk & 15) == 15) {   // flush fp32 chunk into fp64 accumulator
#pragma unroll
                for (int i = 0; i < 4; ++i)
#pragma unroll
                    for (int j = 0; j < 4; ++j) {
                        accd[i][j] += (double)accf[i][j];
                        accf[i][j] = 0.0f;
                    }
            }
        }
    }

#pragma unroll
    for (int i = 0; i < 4; ++i) {
        const size_t tok = tokBase + ty * 4 + i;
        float4 o;
        o.x = (float)accd[i][0]; o.y = (float)accd[i][1];
        o.z = (float)accd[i][2]; o.w = (float)accd[i][3];
        *(float4*)(part + ((size_t)kc * TOKENS + tok) * NEXP + tx * 4) = o;
    }
}

// Kernel 2: wave-per-token fused split-K reduce (fp64) + bias + top-8 + sigmoid.
// Lane e holds logit of expert e; comparisons on the fp32-CAST logit (that is
// what numpy sorts), ties broken toward lower index (lax.top_k stable order).
__global__ __launch_bounds__(256) void router_reduce_topk(
    const float* __restrict__ part, const float* __restrict__ bias,
    float* __restrict__ out_w, float* __restrict__ out_i, int ksplit)
{
    const int lane = threadIdx.x & 63;
    const int wid  = threadIdx.x >> 6;
    const size_t t = (size_t)blockIdx.x * 4 + wid;

    double vd = (double)bias[lane];
    for (int kc = 0; kc < ksplit; ++kc)
        vd += (double)part[((size_t)kc * TOKENS + t) * NEXP + lane];
    float v = (float)vd;

    const int myi = lane;
    float bv = 0.0f; int bi = 0;
#pragma unroll
    for (int r = 0; r < TOPK; ++r) {
        float mv = v; int mi = myi;
#pragma unroll
        for (int off = 32; off > 0; off >>= 1) {
            const float ov = __shfl_xor(mv, off, 64);
            const int   oi = __shfl_xor(mi, off, 64);
            if (ov > mv || (ov == mv && oi < mi)) { mv = ov; mi = oi; }
        }
        if (lane == r)  { bv = mv; bi = mi; }  // lane r keeps rank-r result
        if (myi == mi)  { v = -INFINITY; }     // remove winner (mi is uniform)
    }

    if (lane < TOPK) {
        out_w[t * TOPK + lane] = 1.0f / (1.0f + expf(-bv));
        out_i[t * TOPK + lane] = (float)bi;
    }
}

extern "C" void kernel_launch(void* const* d_in, const int* in_sizes, int n_in,
                              void* d_out, int out_size, void* d_ws, size_t ws_size,
                              hipStream_t stream) {
    const float* x    = (const float*)d_in[0];   // [4,4096,2048]
    const float* W    = (const float*)d_in[1];   // [64,2048]
    const float* bias = (const float*)d_in[2];   // [64]
    float* out_w = (float*)d_out;                          // [16384,8]
    float* out_i = (float*)d_out + (size_t)TOKENS * TOPK;  // [16384,8] as float
    float* part  = (float*)d_ws;                 // [ksplit,16384,64] fp32

    const size_t per = (size_t)TOKENS * NEXP * sizeof(float);
    int ksplit = 8;                      // 2048 blocks keeps all CUs fed
    while (ksplit > 1 && ws_size < (size_t)ksplit * per) ksplit >>= 1;
    const int kchunk = DMODEL / ksplit;

    dim3 grid(TOKENS / BM, ksplit);
    router_gemm<<<grid, 256, 0, stream>>>(x, W, part, kchunk);
    router_reduce_topk<<<TOKENS / 4, 256, 0, stream>>>(part, bias, out_w, out_i, ksplit);
}